// Round 4
// baseline (146.809 us; speedup 1.0000x reference)
//
#include <hip/hip_runtime.h>
#include <math.h>

#define DELTA 0.1f
constexpr int BLOCK = 256;
constexpr int RPT   = 5;   // 4,000,000 rows = 3125 blocks * 256 thr * 5 (exact)

__device__ __forceinline__ float row_loss(float4 p, float4 t) {
    float mp = (p.x + p.y + p.z + p.w) * 0.25f;
    float mt = (t.x + t.y + t.z + t.w) * 0.25f;
    float dpx = p.x - mp, dpy = p.y - mp, dpz = p.z - mp, dpw = p.w - mp;
    float dtx = t.x - mt, dty = t.y - mt, dtz = t.z - mt, dtw = t.w - mt;
    const float inv = 1.0f / 3.0f;  // 1/(D-1)
    float vp  = (dpx*dpx + dpy*dpy + dpz*dpz + dpw*dpw) * inv;
    float vt  = (dtx*dtx + dty*dty + dtz*dtz + dtw*dtw) * inv;
    float cov = (dpx*dtx + dpy*dty + dpz*dtz + dpw*dtw) * inv;
    float a1 = 2.0f * mp * mt + DELTA;
    float a2 = 2.0f * cov + DELTA;
    float b1 = mp * mp + mt * mt + DELTA;
    float b2 = vp + vt + DELTA;
    return 1.0f - (a1 * a2) / (b1 * b2 + DELTA);
}

// Block-contiguous tiling + forced 10-deep load cluster.
__global__ __launch_bounds__(BLOCK) void ssim_partial_kernel(
    const float4* __restrict__ pred,
    const float4* __restrict__ target,
    float* __restrict__ partials,
    int N)
{
    const int tid  = threadIdx.x;
    const int base = blockIdx.x * (BLOCK * RPT);

    float local = 0.0f;

    if (base + BLOCK * RPT <= N) {  // uniform; exact for the bench shape
        // Block streams two dense 80 KB windows; each wave-load = 1 KB segment.
        float4 p[RPT], t[RPT];
        #pragma unroll
        for (int k = 0; k < RPT; ++k) {
            int r = base + k * BLOCK + tid;
            p[k] = pred[r];
            t[k] = target[r];
        }
        // Fence the scheduler: all 10 global_load_dwordx4 issue before any
        // compute is scheduled (compiler otherwise interleaves to VGPR=20
        // and leaves only ~2 loads in flight).
        __builtin_amdgcn_sched_barrier(0);
        #pragma unroll
        for (int k = 0; k < RPT; ++k)
            local += row_loss(p[k], t[k]);
    } else {
        for (int r = base + tid; r < N; r += BLOCK)
            local += row_loss(pred[r], target[r]);
    }

    #pragma unroll
    for (int off = 32; off > 0; off >>= 1)
        local += __shfl_down(local, off, 64);

    __shared__ float wave_sums[BLOCK / 64];
    int lane = tid & 63;
    int wid  = tid >> 6;
    if (lane == 0) wave_sums[wid] = local;
    __syncthreads();

    if (tid == 0)
        partials[blockIdx.x] = wave_sums[0] + wave_sums[1]
                             + wave_sums[2] + wave_sums[3];
}

// One block reduces the per-block partials in f64, applies mean + NaN fallback.
__global__ __launch_bounds__(BLOCK) void ssim_finalize_kernel(
    const float* __restrict__ partials, int nparts,
    float* __restrict__ out, int N)
{
    double local = 0.0;
    for (int i = threadIdx.x; i < nparts; i += BLOCK)
        local += (double)partials[i];

    #pragma unroll
    for (int off = 32; off > 0; off >>= 1)
        local += __shfl_down(local, off, 64);

    __shared__ double wave_sums[BLOCK / 64];
    int lane = threadIdx.x & 63;
    int wid  = threadIdx.x >> 6;
    if (lane == 0) wave_sums[wid] = local;
    __syncthreads();

    if (threadIdx.x == 0) {
        double total = wave_sums[0] + wave_sums[1] + wave_sums[2] + wave_sums[3];
        float f = (float)(total / (double)N);
        if (isnan(f)) f = 1.0f;   // reference NaN fallback == mean(ones) == 1.0
        *out = f;
    }
}

extern "C" void kernel_launch(void* const* d_in, const int* in_sizes, int n_in,
                              void* d_out, int out_size, void* d_ws, size_t ws_size,
                              hipStream_t stream)
{
    const float4* pred   = (const float4*)d_in[0];
    const float4* target = (const float4*)d_in[1];
    int rows = in_sizes[0] / 4;

    int grid = (rows + BLOCK * RPT - 1) / (BLOCK * RPT);  // 3125 at 4M rows
    if (grid < 1) grid = 1;

    float* partials = (float*)d_ws;  // grid * 4 B; every slot overwritten each call

    ssim_partial_kernel<<<grid, BLOCK, 0, stream>>>(pred, target, partials, rows);
    ssim_finalize_kernel<<<1, BLOCK, 0, stream>>>(partials, grid, (float*)d_out, rows);
}